// Round 6
// baseline (523.969 us; speedup 1.0000x reference)
//
#include <hip/hip_runtime.h>
#include <hip/hip_bf16.h>
#include <math.h>

#define NN 50000
#define EE 800000
#define DINK 512
#define DHK 128
#define CK 8
#define KIT 5
#define NBLKS 196  // ceil(NN/256)

typedef __attribute__((ext_vector_type(8))) short short8;
typedef __attribute__((ext_vector_type(4))) float f32x4;

__device__ __forceinline__ unsigned short f2bf(float f) {
    union { float f; unsigned int u; } v;
    v.f = f;
    unsigned int u = v.u;
    unsigned int r = (u + 0x7FFFu + ((u >> 16) & 1u)) >> 16;  // RNE
    return (unsigned short)r;
}
__device__ __forceinline__ float bfu2f(unsigned int lo16) {
    union { unsigned int u; float f; } v;
    v.u = lo16 << 16;
    return v.f;
}

// logH[i][j] = log_sigmoid(param[i][j] + param[j][i]), 8x8
__global__ __launch_bounds__(64) void logH_kernel(const float* __restrict__ param,
                                                  float* __restrict__ logH) {
    int t = threadIdx.x;
    int i = t >> 3, j = t & 7;
    float z = param[i * 8 + j] + param[j * 8 + i];
    logH[t] = fminf(z, 0.0f) - log1pf(expf(-fabsf(z)));
}

// W1 [512][128] fp32 -> W1t [128][512] bf16
__global__ __launch_bounds__(256) void w1t_kernel(const float* __restrict__ W1,
                                                  unsigned short* __restrict__ W1t) {
    int idx = blockIdx.x * 256 + threadIdx.x;  // 65536
    int n = idx >> 9;
    int k = idx & 511;
    W1t[idx] = f2bf(W1[(size_t)k * DHK + n]);
}

// MFMA MLP: logb0 = log_softmax(relu(x@W1+b1)@W2 + b2)
// block=256 (4 waves 2x2), tile 64 rows x 128 hidden -> 782 blocks for occupancy.
__global__ __launch_bounds__(256) void mlp_mfma_kernel(
    const float* __restrict__ x, const unsigned short* __restrict__ W1t,
    const float* __restrict__ b1, const float* __restrict__ W2,
    const float* __restrict__ b2, float* __restrict__ logb0) {
    __shared__ unsigned short hs[64 * 136];
    __shared__ float W2s[128 * 8];
    __shared__ float b1s[128];
    __shared__ float b2s[8];

    const int tid = threadIdx.x;
    const int wave = tid >> 6;
    const int lane = tid & 63;
    const int q = lane >> 4;
    const int lm = lane & 15;
    const int wm = wave >> 1, wn = wave & 1;
    const int n0 = blockIdx.x * 64;

    if (tid < 128) b1s[tid] = b1[tid];
    if (tid < 8) b2s[tid] = b2[tid];
    {
        int i = tid * 4;
        *(float4*)&W2s[i] = *(const float4*)&W2[i];
    }
    __syncthreads();

    const float* xptr[2];
#pragma unroll
    for (int mt = 0; mt < 2; ++mt) {
        int r = n0 + wm * 32 + mt * 16 + lm;
        if (r > NN - 1) r = NN - 1;
        xptr[mt] = x + (size_t)r * DINK + q * 8;
    }
    const unsigned short* bptr[4];
#pragma unroll
    for (int nt = 0; nt < 4; ++nt) {
        int c = wn * 64 + nt * 16 + lm;
        bptr[nt] = W1t + (size_t)c * DINK + q * 8;
    }

    f32x4 acc[2][4];
#pragma unroll
    for (int mt = 0; mt < 2; ++mt)
#pragma unroll
        for (int nt = 0; nt < 4; ++nt) acc[mt][nt] = (f32x4){0.f, 0.f, 0.f, 0.f};

    for (int k0 = 0; k0 < DINK; k0 += 32) {
        short8 af[2], bf[4];
#pragma unroll
        for (int mt = 0; mt < 2; ++mt) {
            float4 u0 = *(const float4*)(xptr[mt] + k0);
            float4 u1 = *(const float4*)(xptr[mt] + k0 + 4);
            union { short8 s; __hip_bfloat162 h[4]; } cv;
            cv.h[0] = __float22bfloat162_rn(make_float2(u0.x, u0.y));
            cv.h[1] = __float22bfloat162_rn(make_float2(u0.z, u0.w));
            cv.h[2] = __float22bfloat162_rn(make_float2(u1.x, u1.y));
            cv.h[3] = __float22bfloat162_rn(make_float2(u1.z, u1.w));
            af[mt] = cv.s;
        }
#pragma unroll
        for (int nt = 0; nt < 4; ++nt) bf[nt] = *(const short8*)(bptr[nt] + k0);
#pragma unroll
        for (int mt = 0; mt < 2; ++mt)
#pragma unroll
            for (int nt = 0; nt < 4; ++nt)
                acc[mt][nt] = __builtin_amdgcn_mfma_f32_16x16x32_bf16(
                    af[mt], bf[nt], acc[mt][nt], 0, 0, 0);
    }

    // bias + relu -> hs bf16. C/D layout: col=lane&15, row=(lane>>4)*4+reg
#pragma unroll
    for (int nt = 0; nt < 4; ++nt) {
        int j = wn * 64 + nt * 16 + lm;
        float bj = b1s[j];
#pragma unroll
        for (int mt = 0; mt < 2; ++mt) {
            int rbase = wm * 32 + mt * 16 + q * 4;
#pragma unroll
            for (int r = 0; r < 4; ++r) {
                float h = fmaxf(acc[mt][nt][r] + bj, 0.0f);
                hs[(rbase + r) * 136 + j] = f2bf(h);
            }
        }
    }
    __syncthreads();

    // second GEMM (128->8) + log_softmax; 4 threads per row (32 dims each)
    int row = tid >> 2;
    int part = tid & 3;
    const unsigned short* hp = &hs[row * 136 + part * 32];
    float p[8] = {0.f, 0.f, 0.f, 0.f, 0.f, 0.f, 0.f, 0.f};
#pragma unroll
    for (int ch = 0; ch < 4; ++ch) {
        uint4 c4 = *(const uint4*)(hp + ch * 8);
        unsigned int uu[4] = {c4.x, c4.y, c4.z, c4.w};
#pragma unroll
        for (int p2 = 0; p2 < 4; ++p2) {
            float h0 = bfu2f(uu[p2] & 0xFFFFu);
            float h1 = bfu2f(uu[p2] >> 16);
            int j = part * 32 + ch * 8 + p2 * 2;
            const float* w0 = &W2s[j * 8];
            const float* w1 = &W2s[(j + 1) * 8];
#pragma unroll
            for (int c = 0; c < 8; ++c) p[c] = fmaf(h0, w0[c], p[c]);
#pragma unroll
            for (int c = 0; c < 8; ++c) p[c] = fmaf(h1, w1[c], p[c]);
        }
    }
#pragma unroll
    for (int off2 = 1; off2 < 4; off2 <<= 1)
#pragma unroll
        for (int c = 0; c < 8; ++c) p[c] += __shfl_xor(p[c], off2, 4);
    int grow = n0 + row;
    if (part == 0 && grow < NN) {
        float v[8];
        float mx = -1e30f;
#pragma unroll
        for (int c = 0; c < 8; ++c) {
            v[c] = p[c] + b2s[c];
            mx = fmaxf(mx, v[c]);
        }
        float s = 0.0f;
#pragma unroll
        for (int c = 0; c < 8; ++c) s += expf(v[c] - mx);
        float ln = mx + logf(s);
        float4* p0 = (float4*)&logb0[(size_t)grow * 8];
        p0[0] = make_float4(v[0] - ln, v[1] - ln, v[2] - ln, v[3] - ln);
        p0[1] = make_float4(v[4] - ln, v[5] - ln, v[6] - ln, v[7] - ln);
    }
}

// ---------------- CSR setup kernels ----------------

__global__ __launch_bounds__(256) void deg_kernel(const int* __restrict__ dst,
                                                  int* __restrict__ cnt) {
    int e = blockIdx.x * 256 + threadIdx.x;
    if (e < EE) atomicAdd(&cnt[dst[e]], 1);
}

__global__ __launch_bounds__(256) void scan_partial_kernel(
    const int* __restrict__ cnt, int* __restrict__ partial) {
    __shared__ int sd[256];
    int t = threadIdx.x;
    int i = blockIdx.x * 256 + t;
    sd[t] = (i < NN) ? cnt[i] : 0;
    __syncthreads();
#pragma unroll
    for (int s = 128; s > 0; s >>= 1) {
        if (t < s) sd[t] += sd[t + s];
        __syncthreads();
    }
    if (t == 0) partial[blockIdx.x] = sd[0];
}

__global__ __launch_bounds__(256) void scan_tops_kernel(
    const int* __restrict__ partial, int* __restrict__ tops) {
    __shared__ int sd[256];
    int t = threadIdx.x;
    sd[t] = (t < NBLKS) ? partial[t] : 0;
    __syncthreads();
#pragma unroll
    for (int s = 1; s < 256; s <<= 1) {
        int a = sd[t];
        int b = (t >= s) ? sd[t - s] : 0;
        __syncthreads();
        sd[t] = a + b;
        __syncthreads();
    }
    if (t < NBLKS) tops[t] = (t > 0) ? sd[t - 1] : 0;
}

__global__ __launch_bounds__(256) void scan_write_kernel(
    const int* __restrict__ cnt, const int* __restrict__ tops,
    int* __restrict__ off) {
    __shared__ int sd[256];
    int t = threadIdx.x;
    int i = blockIdx.x * 256 + t;
    int v = (i < NN) ? cnt[i] : 0;
    sd[t] = v;
    __syncthreads();
#pragma unroll
    for (int s = 1; s < 256; s <<= 1) {
        int a = sd[t];
        int b = (t >= s) ? sd[t - s] : 0;
        __syncthreads();
        sd[t] = a + b;
        __syncthreads();
    }
    if (i < NN) off[i] = tops[blockIdx.x] + sd[t] - v;
    if (i == NN - 1) off[NN] = EE;
}

__global__ __launch_bounds__(256) void pos_kernel(
    const int* __restrict__ src, const int* __restrict__ dst,
    const float* __restrict__ ew, const int* __restrict__ off,
    int* __restrict__ cnt, int* __restrict__ pos,
    int* __restrict__ perm_src, float* __restrict__ perm_w) {
    int e = blockIdx.x * 256 + threadIdx.x;
    if (e >= EE) return;
    int d = dst[e];
    int p = off[d] + atomicAdd(&cnt[d], 1);
    pos[e] = p;
    perm_src[p] = src[e];
    perm_w[p] = ew[e];
}

__global__ __launch_bounds__(256) void rvpos_kernel(const int* __restrict__ rv,
                                                    const int* __restrict__ pos,
                                                    int* __restrict__ perm_rvp) {
    int e = blockIdx.x * 256 + threadIdx.x;
    if (e >= EE) return;
    perm_rvp[pos[e]] = pos[rv[e]];
}

// xin[p] = logb0[perm_src[p]]  (iteration-0 input)
__global__ __launch_bounds__(256) void init_xin_kernel(
    const int* __restrict__ perm_src, const float* __restrict__ logb0,
    float* __restrict__ xin) {
    int p = blockIdx.x * 256 + threadIdx.x;
    if (p >= EE) return;
    int s = perm_src[p];
    const float4* pb = (const float4*)&logb0[(size_t)s * 8];
    float4 a = pb[0], b = pb[1];
    float4* po = (float4*)&xin[(size_t)p * 8];
    po[0] = a;
    po[1] = b;
}

// ---------------- hot loop (fully streaming edge, scatter in node) ---------

__global__ __launch_bounds__(256) void edge_msg_kernel(
    const float* __restrict__ perm_w, const float* __restrict__ logH,
    const float* __restrict__ xin, float* __restrict__ msg_out) {
    __shared__ float lH[64];
    if (threadIdx.x < 64) lH[threadIdx.x] = logH[threadIdx.x];
    __syncthreads();
    int p = blockIdx.x * 256 + threadIdx.x;
    if (p >= EE) return;

    float w = perm_w[p];
    const float4* pb = (const float4*)&xin[(size_t)p * 8];
    float4 v0 = pb[0], v1 = pb[1];
    float xj[8] = {v0.x, v0.y, v0.z, v0.w, v1.x, v1.y, v1.z, v1.w};

    // single stability shift: M = max(xj); w*logH <= 0 so args stay <= 0.
    // The shift cancels exactly in the final normalize.
    float M = xj[0];
#pragma unroll
    for (int c = 1; c < 8; ++c) M = fmaxf(M, xj[c]);
#pragma unroll
    for (int c = 0; c < 8; ++c) xj[c] -= M;

    float mg[8];
#pragma unroll
    for (int c2 = 0; c2 < 8; ++c2) {
        float ssum = 0.0f;
#pragma unroll
        for (int c1 = 0; c1 < 8; ++c1)
            ssum += __expf(fmaf(w, lH[c1 * 8 + c2], xj[c1]));
        mg[c2] = __logf(ssum);
    }
    float mm = mg[0];
#pragma unroll
    for (int c = 1; c < 8; ++c) mm = fmaxf(mm, mg[c]);
    float se = 0.0f;
#pragma unroll
    for (int c = 0; c < 8; ++c) se += __expf(mg[c] - mm);
    float ln = mm + __logf(se);

    float4* po = (float4*)&msg_out[(size_t)p * 8];
    po[0] = make_float4(mg[0] - ln, mg[1] - ln, mg[2] - ln, mg[3] - ln);
    po[1] = make_float4(mg[4] - ln, mg[5] - ln, mg[6] - ln, mg[7] - ln);
}

// 8 threads/node: aggregate in-edge msgs, normalize; then either emit output
// (last iter) or scatter next-iter edge inputs xin[rv(j)] = logb - msg[j].
__global__ __launch_bounds__(256) void node_agg_kernel(
    const float* __restrict__ logb0, const int* __restrict__ off,
    const float* __restrict__ msg, const int* __restrict__ perm_rvp,
    float* __restrict__ xin, float* __restrict__ out, int write_out) {
    int t = blockIdx.x * 256 + threadIdx.x;
    int n = t >> 3;
    int c = t & 7;
    if (n >= NN) return;
    int j0 = off[n], j1 = off[n + 1];
    float a = logb0[(size_t)n * 8 + c];
    for (int j = j0; j < j1; ++j) a += msg[(size_t)j * 8 + c];
    float mx = a;
#pragma unroll
    for (int s = 1; s < 8; s <<= 1) mx = fmaxf(mx, __shfl_xor(mx, s, 8));
    float ex = __expf(a - mx);
    float sum = ex;
#pragma unroll
    for (int s = 1; s < 8; s <<= 1) sum += __shfl_xor(sum, s, 8);
    float v = a - (mx + __logf(sum));
    if (write_out) {
        out[(size_t)n * 8 + c] = v;
    } else {
        for (int j = j0; j < j1; ++j) {
            int r = perm_rvp[j];
            xin[(size_t)r * 8 + c] = v - msg[(size_t)j * 8 + c];
        }
    }
}

extern "C" void kernel_launch(void* const* d_in, const int* in_sizes, int n_in,
                              void* d_out, int out_size, void* d_ws, size_t ws_size,
                              hipStream_t stream) {
    const float* x = (const float*)d_in[0];
    const int* ei = (const int*)d_in[1];
    const float* ew = (const float*)d_in[2];
    const int* rv = (const int*)d_in[3];
    const float* W1 = (const float*)d_in[4];
    const float* b1 = (const float*)d_in[5];
    const float* W2 = (const float*)d_in[6];
    const float* b2 = (const float*)d_in[7];
    const float* param = (const float*)d_in[8];
    float* out = (float*)d_out;

    const int* src = ei;
    const int* dst = ei + EE;

    float* wsf = (float*)d_ws;
    float* logH = wsf;                          // 64
    float* logb0 = logH + 64;                   // 400000
    float* msg = logb0 + (size_t)NN * 8;        // 6.4M
    float* xin = msg + (size_t)EE * 8;          // 6.4M
    float* perm_w = xin + (size_t)EE * 8;       // 800000
    int* off = (int*)(perm_w + EE);             // 50001
    int* perm_src = off + (NN + 1);             // 800000
    int* perm_rvp = perm_src + EE;              // 800000
    unsigned short* W1t = (unsigned short*)(perm_rvp + EE);  // 65536 bf16
    // setup-only scratch aliases xin (xin first written by init_xin after setup)
    int* pos = (int*)xin;                       // 800000
    int* cnt = pos + EE;                        // 50000
    int* partial = cnt + NN;                    // 196
    int* tops = partial + NBLKS;                // 196

    logH_kernel<<<1, 64, 0, stream>>>(param, logH);
    w1t_kernel<<<256, 256, 0, stream>>>(W1, W1t);
    mlp_mfma_kernel<<<(NN + 63) / 64, 256, 0, stream>>>(x, W1t, b1, W2, b2, logb0);

    const int EB = (EE + 255) / 256;

    hipMemsetAsync(cnt, 0, (size_t)NN * sizeof(int), stream);
    deg_kernel<<<EB, 256, 0, stream>>>(dst, cnt);
    scan_partial_kernel<<<NBLKS, 256, 0, stream>>>(cnt, partial);
    scan_tops_kernel<<<1, 256, 0, stream>>>(partial, tops);
    scan_write_kernel<<<NBLKS, 256, 0, stream>>>(cnt, tops, off);
    hipMemsetAsync(cnt, 0, (size_t)NN * sizeof(int), stream);
    pos_kernel<<<EB, 256, 0, stream>>>(src, dst, ew, off, cnt, pos, perm_src, perm_w);
    rvpos_kernel<<<EB, 256, 0, stream>>>(rv, pos, perm_rvp);
    init_xin_kernel<<<EB, 256, 0, stream>>>(perm_src, logb0, xin);

    for (int it = 0; it < KIT; ++it) {
        edge_msg_kernel<<<EB, 256, 0, stream>>>(perm_w, logH, xin, msg);
        node_agg_kernel<<<(NN * 8 + 255) / 256, 256, 0, stream>>>(
            logb0, off, msg, perm_rvp, xin, out, it == KIT - 1 ? 1 : 0);
    }
}

// Round 7
// 497.466 us; speedup vs baseline: 1.0533x; 1.0533x over previous
//
#include <hip/hip_runtime.h>
#include <hip/hip_bf16.h>
#include <math.h>

#define NN 50000
#define EE 800000
#define DINK 512
#define DHK 128
#define CK 8
#define KIT 5
#define NBLKS 196  // ceil(NN/256)

typedef __attribute__((ext_vector_type(8))) short short8;
typedef __attribute__((ext_vector_type(4))) float f32x4;

__device__ __forceinline__ unsigned short f2bf(float f) {
    union { float f; unsigned int u; } v;
    v.f = f;
    unsigned int u = v.u;
    unsigned int r = (u + 0x7FFFu + ((u >> 16) & 1u)) >> 16;  // RNE
    return (unsigned short)r;
}
__device__ __forceinline__ float bfu2f(unsigned int lo16) {
    union { unsigned int u; float f; } v;
    v.u = lo16 << 16;
    return v.f;
}

// logH[i][j] = log_sigmoid(param[i][j] + param[j][i]), 8x8
__global__ __launch_bounds__(64) void logH_kernel(const float* __restrict__ param,
                                                  float* __restrict__ logH) {
    int t = threadIdx.x;
    int i = t >> 3, j = t & 7;
    float z = param[i * 8 + j] + param[j * 8 + i];
    logH[t] = fminf(z, 0.0f) - log1pf(expf(-fabsf(z)));
}

// W1 [512][128] fp32 -> W1t [128][512] bf16
__global__ __launch_bounds__(256) void w1t_kernel(const float* __restrict__ W1,
                                                  unsigned short* __restrict__ W1t) {
    int idx = blockIdx.x * 256 + threadIdx.x;  // 65536
    int n = idx >> 9;
    int k = idx & 511;
    W1t[idx] = f2bf(W1[(size_t)k * DHK + n]);
}

// MFMA MLP: logb0 = log_softmax(relu(x@W1+b1)@W2 + b2)
// block=256 (4 waves 2x2), tile 128 rows x 128 hidden, K-loop direct-from-global
// with 1-deep register prefetch (loads for k0+32 in flight during k0's MFMAs).
__global__ __launch_bounds__(256) void mlp_mfma_kernel(
    const float* __restrict__ x, const unsigned short* __restrict__ W1t,
    const float* __restrict__ b1, const float* __restrict__ W2,
    const float* __restrict__ b2, float* __restrict__ logb0) {
    __shared__ unsigned short hs[128 * 136];
    __shared__ float W2s[128 * 8];
    __shared__ float b1s[128];
    __shared__ float b2s[8];

    const int tid = threadIdx.x;
    const int wave = tid >> 6;
    const int lane = tid & 63;
    const int q = lane >> 4;
    const int lm = lane & 15;
    const int wm = wave >> 1, wn = wave & 1;
    const int n0 = blockIdx.x * 128;

    if (tid < 128) b1s[tid] = b1[tid];
    if (tid < 8) b2s[tid] = b2[tid];
    {
        int i = tid * 4;
        *(float4*)&W2s[i] = *(const float4*)&W2[i];
    }
    __syncthreads();

    const float* xptr[4];
#pragma unroll
    for (int mt = 0; mt < 4; ++mt) {
        int r = n0 + wm * 64 + mt * 16 + lm;
        if (r > NN - 1) r = NN - 1;
        xptr[mt] = x + (size_t)r * DINK + q * 8;
    }
    const unsigned short* bptr[4];
#pragma unroll
    for (int nt = 0; nt < 4; ++nt) {
        int c = wn * 64 + nt * 16 + lm;
        bptr[nt] = W1t + (size_t)c * DINK + q * 8;
    }

    f32x4 acc[4][4];
#pragma unroll
    for (int mt = 0; mt < 4; ++mt)
#pragma unroll
        for (int nt = 0; nt < 4; ++nt) acc[mt][nt] = (f32x4){0.f, 0.f, 0.f, 0.f};

    // software pipeline: raw fp32 A + bf16 B one k0-step ahead
    float4 ar[4][2];
    short8 bc[4];
#pragma unroll
    for (int mt = 0; mt < 4; ++mt) {
        ar[mt][0] = *(const float4*)(xptr[mt]);
        ar[mt][1] = *(const float4*)(xptr[mt] + 4);
    }
#pragma unroll
    for (int nt = 0; nt < 4; ++nt) bc[nt] = *(const short8*)(bptr[nt]);

#pragma unroll
    for (int k0 = 32; k0 <= DINK; k0 += 32) {
        float4 ar2[4][2];
        short8 b2f[4];
        if (k0 < DINK) {
#pragma unroll
            for (int mt = 0; mt < 4; ++mt) {
                ar2[mt][0] = *(const float4*)(xptr[mt] + k0);
                ar2[mt][1] = *(const float4*)(xptr[mt] + k0 + 4);
            }
#pragma unroll
            for (int nt = 0; nt < 4; ++nt)
                b2f[nt] = *(const short8*)(bptr[nt] + k0);
        }
        // convert current A to bf16 and MFMA
        short8 af[4];
#pragma unroll
        for (int mt = 0; mt < 4; ++mt) {
            union { short8 s; __hip_bfloat162 h[4]; } cv;
            cv.h[0] = __float22bfloat162_rn(make_float2(ar[mt][0].x, ar[mt][0].y));
            cv.h[1] = __float22bfloat162_rn(make_float2(ar[mt][0].z, ar[mt][0].w));
            cv.h[2] = __float22bfloat162_rn(make_float2(ar[mt][1].x, ar[mt][1].y));
            cv.h[3] = __float22bfloat162_rn(make_float2(ar[mt][1].z, ar[mt][1].w));
            af[mt] = cv.s;
        }
#pragma unroll
        for (int mt = 0; mt < 4; ++mt)
#pragma unroll
            for (int nt = 0; nt < 4; ++nt)
                acc[mt][nt] = __builtin_amdgcn_mfma_f32_16x16x32_bf16(
                    af[mt], bc[nt], acc[mt][nt], 0, 0, 0);
        if (k0 < DINK) {
#pragma unroll
            for (int mt = 0; mt < 4; ++mt) {
                ar[mt][0] = ar2[mt][0];
                ar[mt][1] = ar2[mt][1];
            }
#pragma unroll
            for (int nt = 0; nt < 4; ++nt) bc[nt] = b2f[nt];
        }
    }

    // bias + relu -> hs bf16. C/D layout: col=lane&15, row=(lane>>4)*4+reg
#pragma unroll
    for (int nt = 0; nt < 4; ++nt) {
        int j = wn * 64 + nt * 16 + lm;
        float bj = b1s[j];
#pragma unroll
        for (int mt = 0; mt < 4; ++mt) {
            int rbase = wm * 64 + mt * 16 + q * 4;
#pragma unroll
            for (int r = 0; r < 4; ++r) {
                float h = fmaxf(acc[mt][nt][r] + bj, 0.0f);
                hs[(rbase + r) * 136 + j] = f2bf(h);
            }
        }
    }
    __syncthreads();

    // second GEMM (128->8) + log_softmax; 2 threads per row
    int row = tid >> 1;
    int half = tid & 1;
    const unsigned short* hp = &hs[row * 136 + half * 64];
    float p[8] = {0.f, 0.f, 0.f, 0.f, 0.f, 0.f, 0.f, 0.f};
#pragma unroll
    for (int ch = 0; ch < 8; ++ch) {
        uint4 c4 = *(const uint4*)(hp + ch * 8);
        unsigned int uu[4] = {c4.x, c4.y, c4.z, c4.w};
#pragma unroll
        for (int p2 = 0; p2 < 4; ++p2) {
            float h0 = bfu2f(uu[p2] & 0xFFFFu);
            float h1 = bfu2f(uu[p2] >> 16);
            int j = half * 64 + ch * 8 + p2 * 2;
            const float* w0 = &W2s[j * 8];
            const float* w1 = &W2s[(j + 1) * 8];
#pragma unroll
            for (int c = 0; c < 8; ++c) p[c] = fmaf(h0, w0[c], p[c]);
#pragma unroll
            for (int c = 0; c < 8; ++c) p[c] = fmaf(h1, w1[c], p[c]);
        }
    }
#pragma unroll
    for (int c = 0; c < 8; ++c) p[c] += __shfl_xor(p[c], 1, 64);
    int grow = n0 + row;
    if (half == 0 && grow < NN) {
        float v[8];
        float mx = -1e30f;
#pragma unroll
        for (int c = 0; c < 8; ++c) {
            v[c] = p[c] + b2s[c];
            mx = fmaxf(mx, v[c]);
        }
        float s = 0.0f;
#pragma unroll
        for (int c = 0; c < 8; ++c) s += expf(v[c] - mx);
        float ln = mx + logf(s);
        float4* p0 = (float4*)&logb0[(size_t)grow * 8];
        p0[0] = make_float4(v[0] - ln, v[1] - ln, v[2] - ln, v[3] - ln);
        p0[1] = make_float4(v[4] - ln, v[5] - ln, v[6] - ln, v[7] - ln);
    }
}

// ---------------- CSR setup kernels ----------------

__global__ __launch_bounds__(256) void deg_kernel(const int* __restrict__ dst,
                                                  int* __restrict__ cnt) {
    int e = blockIdx.x * 256 + threadIdx.x;
    if (e < EE) atomicAdd(&cnt[dst[e]], 1);
}

__global__ __launch_bounds__(256) void scan_partial_kernel(
    const int* __restrict__ cnt, int* __restrict__ partial) {
    __shared__ int sd[256];
    int t = threadIdx.x;
    int i = blockIdx.x * 256 + t;
    sd[t] = (i < NN) ? cnt[i] : 0;
    __syncthreads();
#pragma unroll
    for (int s = 128; s > 0; s >>= 1) {
        if (t < s) sd[t] += sd[t + s];
        __syncthreads();
    }
    if (t == 0) partial[blockIdx.x] = sd[0];
}

__global__ __launch_bounds__(256) void scan_tops_kernel(
    const int* __restrict__ partial, int* __restrict__ tops) {
    __shared__ int sd[256];
    int t = threadIdx.x;
    sd[t] = (t < NBLKS) ? partial[t] : 0;
    __syncthreads();
#pragma unroll
    for (int s = 1; s < 256; s <<= 1) {
        int a = sd[t];
        int b = (t >= s) ? sd[t - s] : 0;
        __syncthreads();
        sd[t] = a + b;
        __syncthreads();
    }
    if (t < NBLKS) tops[t] = (t > 0) ? sd[t - 1] : 0;
}

__global__ __launch_bounds__(256) void scan_write_kernel(
    const int* __restrict__ cnt, const int* __restrict__ tops,
    int* __restrict__ off) {
    __shared__ int sd[256];
    int t = threadIdx.x;
    int i = blockIdx.x * 256 + t;
    int v = (i < NN) ? cnt[i] : 0;
    sd[t] = v;
    __syncthreads();
#pragma unroll
    for (int s = 1; s < 256; s <<= 1) {
        int a = sd[t];
        int b = (t >= s) ? sd[t - s] : 0;
        __syncthreads();
        sd[t] = a + b;
        __syncthreads();
    }
    if (i < NN) off[i] = tops[blockIdx.x] + sd[t] - v;
    if (i == NN - 1) off[NN] = EE;
}

// packed (src, w-bits) pair, one 8B store per edge
__global__ __launch_bounds__(256) void pos_kernel(
    const int* __restrict__ src, const int* __restrict__ dst,
    const float* __restrict__ ew, const int* __restrict__ off,
    int* __restrict__ cnt, int* __restrict__ pos,
    int2* __restrict__ perm_sw) {
    int e = blockIdx.x * 256 + threadIdx.x;
    if (e >= EE) return;
    int d = dst[e];
    int p = off[d] + atomicAdd(&cnt[d], 1);
    pos[e] = p;
    int2 sw;
    sw.x = src[e];
    sw.y = __float_as_int(ew[e]);
    perm_sw[p] = sw;
}

__global__ __launch_bounds__(256) void rvpos_kernel(const int* __restrict__ rv,
                                                    const int* __restrict__ pos,
                                                    int* __restrict__ perm_rvp) {
    int e = blockIdx.x * 256 + threadIdx.x;
    if (e >= EE) return;
    perm_rvp[pos[e]] = pos[rv[e]];
}

// xin[p] = logb0[perm_src[p]]; also unpack perm_w
__global__ __launch_bounds__(256) void init_xin_kernel(
    const int2* __restrict__ perm_sw, const float* __restrict__ logb0,
    float* __restrict__ xin, float* __restrict__ perm_w) {
    int p = blockIdx.x * 256 + threadIdx.x;
    if (p >= EE) return;
    int2 sw = perm_sw[p];
    perm_w[p] = __int_as_float(sw.y);
    const float4* pb = (const float4*)&logb0[(size_t)sw.x * 8];
    float4 a = pb[0], b = pb[1];
    float4* po = (float4*)&xin[(size_t)p * 8];
    po[0] = a;
    po[1] = b;
}

// ---------------- hot loop (streaming edge, scatter in node) ---------------

__global__ __launch_bounds__(256) void edge_msg_kernel(
    const float* __restrict__ perm_w, const float* __restrict__ logH,
    const float* __restrict__ xin, float* __restrict__ msg_out) {
    __shared__ float lH[64];
    if (threadIdx.x < 64) lH[threadIdx.x] = logH[threadIdx.x];
    __syncthreads();
    int p = blockIdx.x * 256 + threadIdx.x;
    if (p >= EE) return;

    float w = perm_w[p];
    const float4* pb = (const float4*)&xin[(size_t)p * 8];
    float4 v0 = pb[0], v1 = pb[1];
    float xj[8] = {v0.x, v0.y, v0.z, v0.w, v1.x, v1.y, v1.z, v1.w};

    float M = xj[0];
#pragma unroll
    for (int c = 1; c < 8; ++c) M = fmaxf(M, xj[c]);
#pragma unroll
    for (int c = 0; c < 8; ++c) xj[c] -= M;

    float mg[8];
#pragma unroll
    for (int c2 = 0; c2 < 8; ++c2) {
        float ssum = 0.0f;
#pragma unroll
        for (int c1 = 0; c1 < 8; ++c1)
            ssum += __expf(fmaf(w, lH[c1 * 8 + c2], xj[c1]));
        mg[c2] = __logf(ssum);
    }
    float mm = mg[0];
#pragma unroll
    for (int c = 1; c < 8; ++c) mm = fmaxf(mm, mg[c]);
    float se = 0.0f;
#pragma unroll
    for (int c = 0; c < 8; ++c) se += __expf(mg[c] - mm);
    float ln = mm + __logf(se);

    float4* po = (float4*)&msg_out[(size_t)p * 8];
    po[0] = make_float4(mg[0] - ln, mg[1] - ln, mg[2] - ln, mg[3] - ln);
    po[1] = make_float4(mg[4] - ln, mg[5] - ln, mg[6] - ln, mg[7] - ln);
}

__global__ __launch_bounds__(256) void node_agg_kernel(
    const float* __restrict__ logb0, const int* __restrict__ off,
    const float* __restrict__ msg, const int* __restrict__ perm_rvp,
    float* __restrict__ xin, float* __restrict__ out, int write_out) {
    int t = blockIdx.x * 256 + threadIdx.x;
    int n = t >> 3;
    int c = t & 7;
    if (n >= NN) return;
    int j0 = off[n], j1 = off[n + 1];
    float a = logb0[(size_t)n * 8 + c];
    for (int j = j0; j < j1; ++j) a += msg[(size_t)j * 8 + c];
    float mx = a;
#pragma unroll
    for (int s = 1; s < 8; s <<= 1) mx = fmaxf(mx, __shfl_xor(mx, s, 8));
    float ex = __expf(a - mx);
    float sum = ex;
#pragma unroll
    for (int s = 1; s < 8; s <<= 1) sum += __shfl_xor(sum, s, 8);
    float v = a - (mx + __logf(sum));
    if (write_out) {
        out[(size_t)n * 8 + c] = v;
    } else {
        for (int j = j0; j < j1; ++j) {
            int r = perm_rvp[j];
            xin[(size_t)r * 8 + c] = v - msg[(size_t)j * 8 + c];
        }
    }
}

extern "C" void kernel_launch(void* const* d_in, const int* in_sizes, int n_in,
                              void* d_out, int out_size, void* d_ws, size_t ws_size,
                              hipStream_t stream) {
    const float* x = (const float*)d_in[0];
    const int* ei = (const int*)d_in[1];
    const float* ew = (const float*)d_in[2];
    const int* rv = (const int*)d_in[3];
    const float* W1 = (const float*)d_in[4];
    const float* b1 = (const float*)d_in[5];
    const float* W2 = (const float*)d_in[6];
    const float* b2 = (const float*)d_in[7];
    const float* param = (const float*)d_in[8];
    float* out = (float*)d_out;

    const int* src = ei;
    const int* dst = ei + EE;

    float* wsf = (float*)d_ws;
    float* logH = wsf;                          // 64
    float* logb0 = logH + 64;                   // 400000
    float* msg = logb0 + (size_t)NN * 8;        // 6.4M
    float* xin = msg + (size_t)EE * 8;          // 6.4M
    float* perm_w = xin + (size_t)EE * 8;       // 800000
    int* off = (int*)(perm_w + EE);             // 50001
    int2* perm_sw = (int2*)(off + (NN + 1));    // 800000 int2
    int* perm_rvp = (int*)(perm_sw + EE);       // 800000
    unsigned short* W1t = (unsigned short*)(perm_rvp + EE);  // 65536 bf16
    // setup-only scratch aliases xin (xin first written by init_xin after setup)
    int* pos = (int*)xin;                       // 800000
    int* cnt = pos + EE;                        // 50000
    int* partial = cnt + NN;                    // 196
    int* tops = partial + NBLKS;                // 196

    logH_kernel<<<1, 64, 0, stream>>>(param, logH);
    w1t_kernel<<<256, 256, 0, stream>>>(W1, W1t);
    mlp_mfma_kernel<<<(NN + 127) / 128, 256, 0, stream>>>(x, W1t, b1, W2, b2,
                                                          logb0);

    const int EB = (EE + 255) / 256;

    hipMemsetAsync(cnt, 0, (size_t)NN * sizeof(int), stream);
    deg_kernel<<<EB, 256, 0, stream>>>(dst, cnt);
    scan_partial_kernel<<<NBLKS, 256, 0, stream>>>(cnt, partial);
    scan_tops_kernel<<<1, 256, 0, stream>>>(partial, tops);
    scan_write_kernel<<<NBLKS, 256, 0, stream>>>(cnt, tops, off);
    hipMemsetAsync(cnt, 0, (size_t)NN * sizeof(int), stream);
    pos_kernel<<<EB, 256, 0, stream>>>(src, dst, ew, off, cnt, pos, perm_sw);
    rvpos_kernel<<<EB, 256, 0, stream>>>(rv, pos, perm_rvp);
    init_xin_kernel<<<EB, 256, 0, stream>>>(perm_sw, logb0, xin, perm_w);

    for (int it = 0; it < KIT; ++it) {
        edge_msg_kernel<<<EB, 256, 0, stream>>>(perm_w, logH, xin, msg);
        node_agg_kernel<<<(NN * 8 + 255) / 256, 256, 0, stream>>>(
            logb0, off, msg, perm_rvp, xin, out, it == KIT - 1 ? 1 : 0);
    }
}